// Round 9
// baseline (1070.944 us; speedup 1.0000x reference)
//
#include <hip/hip_runtime.h>
#include <float.h>
#include <stdint.h>

// Problem constants
constexpr int D      = 256;
constexpr int K      = 8192;
constexpr int NROWS  = 16384;   // 16 * 32 * 32
constexpr int BHW    = 1024;
constexpr float MARGIN = 8e-4f; // rigorous need: 5.8e-4 (2*bf16 err + 2 buckets) + pack slop

typedef __bf16 bf16x8 __attribute__((ext_vector_type(8)));
typedef float  f32x4  __attribute__((ext_vector_type(4)));
typedef unsigned short ushort4v __attribute__((ext_vector_type(4)));

// ---- contraction-proof f32 ops (round exactly like numpy's elementwise)
__device__ __forceinline__ float mul_rn(float a, float b) {
#pragma clang fp contract(off)
    return a * b;
}
__device__ __forceinline__ float add_rn(float a, float b) {
#pragma clang fp contract(off)
    return a + b;
}
__device__ __forceinline__ float sub_rn(float a, float b) {
#pragma clang fp contract(off)
    return a - b;
}

__device__ __forceinline__ unsigned short f32_bf16_rn(float f) {
    unsigned u = __float_as_uint(f);
    return (unsigned short)((u + 0x7FFFu + ((u >> 16) & 1u)) >> 16);
}

__device__ __forceinline__ unsigned umin_(unsigned a, unsigned b) { return a < b ? a : b; }
__device__ __forceinline__ unsigned umax_(unsigned a, unsigned b) { return a > b ? a : b; }

// monotone float->u32 key: order(key) == order(float)
__device__ __forceinline__ unsigned mono_key(float s) {
    unsigned b = __float_as_uint(s);
    return b ^ ((unsigned)((int)b >> 31) | 0x80000000u);
}
__device__ __forceinline__ float inv_mono(unsigned k) {
    unsigned m = (k & 0x80000000u) ? 0x80000000u : 0xFFFFFFFFu;
    return __uint_as_float(k ^ m);
}

// ---------------- K1: x (B,C,H,W) -> xT[n][256] f32 + Xbf[n][256] bf16
__global__ __launch_bounds__(256)
void prep_x_kernel(const float* __restrict__ x, float* __restrict__ xT,
                   unsigned short* __restrict__ Xbf) {
    __shared__ float t[32][33];
    const int tid = threadIdx.x;
    const int tx = tid & 31, ty = tid >> 5;
    const int ht = blockIdx.x & 31;
    const int dt = (blockIdx.x >> 5) & 7;
    const int b  = blockIdx.x >> 8;
    #pragma unroll
    for (int r = 0; r < 4; ++r) {
        int dl = ty + 8 * r;
        t[dl][tx] = x[(size_t)(b * 256 + dt * 32 + dl) * BHW + ht * 32 + tx];
    }
    __syncthreads();
    #pragma unroll
    for (int r = 0; r < 4; ++r) {
        int hwl = ty + 8 * r;
        int n = b * BHW + ht * 32 + hwl;
        float f = t[tx][hwl];
        xT[(size_t)n * 256 + dt * 32 + tx] = f;
        Xbf[(size_t)n * 256 + dt * 32 + tx] = f32_bf16_rn(f);
    }
}

// ---------------- K2: cb -> Cbf bf16
__global__ __launch_bounds__(256)
void prep_c_kernel(const float* __restrict__ cb, unsigned short* __restrict__ Cbf) {
    int t = blockIdx.x * 256 + threadIdx.x;   // one float4 (524288 total)
    float4 v = ((const float4*)cb)[t];
    ushort4v h;
    h.x = f32_bf16_rn(v.x); h.y = f32_bf16_rn(v.y);
    h.z = f32_bf16_rn(v.z); h.w = f32_bf16_rn(v.w);
    *(ushort4v*)(Cbf + (size_t)t * 4) = h;
}

// ---------------- K3: np-exact sum of squares, wave-parallel (bit-exact
// replica of numpy pairwise order for n=256: 2 halves x 8 chains x 16 adds)
__global__ __launch_bounds__(256)
void sumsq_kernel(const float* __restrict__ rows, float* __restrict__ out, int nrows) {
    const int tid  = threadIdx.x;
    const int ln   = tid & 63;
    const int sub  = ln & 15;
    const int h    = sub >> 3;
    const int j    = sub & 7;
    const int row  = blockIdx.x * 16 + (tid >> 4);
    if (row >= nrows) return;
    const float* p = rows + (size_t)row * 256 + h * 128 + j;
    float v = p[0];
    float r = mul_rn(v, v);
    #pragma unroll
    for (int i = 1; i < 16; ++i) {
        v = p[i * 8];
        r = add_rn(r, mul_rn(v, v));
    }
    float s = add_rn(r, __shfl_xor(r, 1, 64));
    s = add_rn(s, __shfl_xor(s, 2, 64));
    s = add_rn(s, __shfl_xor(s, 4, 64));
    float o = __shfl_xor(s, 8, 64);
    if (sub == 0) out[row] = add_rn(s, o);
}

// ---------------- K5: bf16 MFMA screen, packed-key top-3 per (row, 128-block)
// Wave-tile 32x64 (acc=32 VGPR) for occupancy; grid (64 col-tiles, 256
// row-tiles) so XCD = bx%8 pins 512 KB of Cbf per XCD L2. Outputs [block][n].
__global__ __launch_bounds__(256, 4)
void screen_kernel(const unsigned short* __restrict__ Xbf,  // [16384][256]
                   const unsigned short* __restrict__ Cbf,  // [8192][256]
                   const float* __restrict__ csq,
                   unsigned* __restrict__ sv0, unsigned* __restrict__ sv1,
                   unsigned* __restrict__ sv2) {
    __shared__ unsigned lmk0[128], lmk1[128], lmk2[128];

    const int tid = threadIdx.x;
    const int w   = tid >> 6;
    const int ln  = tid & 63;
    const int bx = blockIdx.x;      // col-tile (128 cols), 0..63  -- fast dim
    const int by = blockIdx.y;      // row-tile (64 rows),  0..255

    const int rh = (w & 1) * 32;    // wave's row sub-strip
    const int ch = (w >> 1) * 64;   // wave's col half

    const int row0 = by * 64 + rh + (ln & 15);
    const int col0 = bx * 128 + ch + (ln & 15);
    const int kq   = (ln >> 4) * 8;
    const unsigned short* pa = Xbf + (size_t)row0 * 256 + kq;
    const unsigned short* pb = Cbf + (size_t)col0 * 256 + kq;

    f32x4 acc[2][4] = {};

    #pragma unroll
    for (int ks = 0; ks < 8; ++ks) {            // K = 256, 32 per step
        const int kb = ks * 32;
        bf16x8 af[2], bfr[4];
        #pragma unroll
        for (int t = 0; t < 2; ++t)
            af[t]  = *(const bf16x8*)(pa + (size_t)(t * 16) * 256 + kb);
        #pragma unroll
        for (int t = 0; t < 4; ++t)
            bfr[t] = *(const bf16x8*)(pb + (size_t)(t * 16) * 256 + kb);
        #pragma unroll
        for (int i = 0; i < 2; ++i)
            #pragma unroll
            for (int j = 0; j < 4; ++j)
                acc[i][j] = __builtin_amdgcn_mfma_f32_16x16x32_bf16(af[i], bfr[j], acc[i][j], 0, 0, 0);
    }

    float cq[4];
    #pragma unroll
    for (int j = 0; j < 4; ++j)
        cq[j] = csq[bx * 128 + ch + j * 16 + (ln & 15)];

    #pragma unroll
    for (int i = 0; i < 2; ++i)
        #pragma unroll
        for (int r = 0; r < 4; ++r) {
            unsigned k[4];
            #pragma unroll
            for (int j = 0; j < 4; ++j) {
                float s = fmaf(-2.0f, acc[i][j][r], cq[j]);   // == rn(cq - 2*acc)
                k[j] = (mono_key(s) & 0xFFFFFF80u) | (unsigned)(ch + j * 16 + (ln & 15));
            }
            // sort4 -> smallest 3
            unsigned t0 = umin_(k[0], k[1]), t1 = umax_(k[0], k[1]);
            unsigned t2 = umin_(k[2], k[3]), t3 = umax_(k[2], k[3]);
            unsigned a0 = umin_(t0, t2);
            unsigned u  = umax_(t0, t2), v = umin_(t1, t3);
            unsigned a1 = umin_(u, v);
            unsigned a2 = umax_(u, v);
            // 16-lane butterfly merge of sorted triples
            #pragma unroll
            for (int m = 1; m < 16; m <<= 1) {
                unsigned b0 = __shfl_xor(a0, m, 64);
                unsigned b1 = __shfl_xor(a1, m, 64);
                unsigned b2 = __shfl_xor(a2, m, 64);
                unsigned uu = umax_(a0, b0), tt = umin_(a1, b1);
                unsigned n0 = umin_(a0, b0);
                unsigned n1 = umin_(uu, tt);
                unsigned n2 = umin_(umin_(a2, b2), umax_(uu, tt));
                a0 = n0; a1 = n1; a2 = n2;
            }
            if ((ln & 15) == 0) {
                int lrow = rh + i * 16 + (ln >> 4) * 4 + r;   // 0..63
                int half = w >> 1;
                lmk0[lrow * 2 + half] = a0;
                lmk1[lrow * 2 + half] = a1;
                lmk2[lrow * 2 + half] = a2;
            }
        }
    __syncthreads();
    if (tid < 64) {
        unsigned q0 = lmk0[tid * 2], q1 = lmk1[tid * 2], q2 = lmk2[tid * 2];
        unsigned p0 = lmk0[tid * 2 + 1], p1 = lmk1[tid * 2 + 1], p2 = lmk2[tid * 2 + 1];
        unsigned uu = umax_(q0, p0), tt = umin_(q1, p1);
        unsigned n0 = umin_(q0, p0);
        unsigned n1 = umin_(uu, tt);
        unsigned n2 = umin_(umin_(q2, p2), umax_(uu, tt));
        size_t o = (size_t)bx * NROWS + by * 64 + tid;
        sv0[o] = n0; sv1[o] = n1; sv2[o] = n2;
    }
}

// ---------------- K6: fused flag + exact rescore -> idx[n]  (1 wave / row)
__global__ __launch_bounds__(256)
void rescore_kernel(const float* __restrict__ xT, const float* __restrict__ cb,
                    const float* __restrict__ csq, const float* __restrict__ xsq,
                    const unsigned* __restrict__ sv0, const unsigned* __restrict__ sv1,
                    const unsigned* __restrict__ sv2,
                    int* __restrict__ idx) {
    const int tid = threadIdx.x;
    const int w = tid >> 6, ln = tid & 63;
    const int n = blockIdx.x * 4 + w;
    unsigned k0 = sv0[(size_t)ln * NROWS + n];
    unsigned k1 = sv1[(size_t)ln * NROWS + n];
    unsigned k2 = sv2[(size_t)ln * NROWS + n];
    // global min key over 64 blocks
    unsigned g = k0;
    #pragma unroll
    for (int m = 1; m < 64; m <<= 1) g = umin_(g, __shfl_xor(g, m, 64));
    float th = inv_mono(g & 0xFFFFFF80u) + MARGIN;
    unsigned th_key = mono_key(th) | 127u;
    unsigned long long m1 = __ballot(k0 <= th_key);   // block winner is candidate
    unsigned long long m2 = __ballot(k1 <= th_key);   // runner-up is candidate
    unsigned long long m3 = __ballot(k2 <= th_key);   // >=3 near-ties: full scan

    float4 xv = ((const float4*)xT)[(size_t)n * 64 + ln];
    const float xs = xsq[n];
    float bs = FLT_MAX;
    int   bk = 0x7fffffff;
    auto eval = [&](int k) {
        float4 cv = ((const float4*)cb)[(size_t)k * 64 + ln];
        double d = (double)cv.x * xv.x + (double)cv.y * xv.y
                 + (double)cv.z * xv.z + (double)cv.w * xv.w;
        #pragma unroll
        for (int m = 1; m < 64; m <<= 1) d += __shfl_xor(d, m, 64);
        float s = sub_rn(add_rn(xs, csq[k]), mul_rn(2.0f, (float)d));
        if (s < bs || (s == bs && k < bk)) { bs = s; bk = k; }
    };
    while (m1) {
        int b = (int)__builtin_ctzll(m1); m1 &= m1 - 1;
        unsigned kb = __shfl((int)k0, b, 64);
        eval(b * 128 + (int)(kb & 127u));
    }
    while (m2) {
        int b = (int)__builtin_ctzll(m2); m2 &= m2 - 1;
        unsigned kb = __shfl((int)k1, b, 64);
        eval(b * 128 + (int)(kb & 127u));
    }
    while (m3) {   // rare rigorous fallback
        int b = (int)__builtin_ctzll(m3); m3 &= m3 - 1;
        for (int kk = 0; kk < 128; ++kk) eval(b * 128 + kk);
    }
    if (ln == 0) idx[n] = bk;
}

// ---------------- K7: quantized gather back to (B,C,H,W)
__global__ __launch_bounds__(256)
void gather_quant_kernel(const float* __restrict__ cb, const int* __restrict__ idx,
                         float* __restrict__ out0) {
    int t = blockIdx.x * 256 + threadIdx.x;
    int hw4 = t & 255;
    int d   = (t >> 8) & 255;
    int b   = t >> 16;
    int n0  = b * BHW + hw4 * 4;
    float4 o;
    o.x = cb[(size_t)idx[n0 + 0] * D + d];
    o.y = cb[(size_t)idx[n0 + 1] * D + d];
    o.z = cb[(size_t)idx[n0 + 2] * D + d];
    o.w = cb[(size_t)idx[n0 + 3] * D + d];
    ((float4*)out0)[t] = o;
}

// ---------------- K8: one-hot fill
__global__ __launch_bounds__(256)
void onehot_kernel(const int* __restrict__ idx, float* __restrict__ out1) {
    int t = blockIdx.x * 256 + threadIdx.x;
    int n  = t >> 11;
    int k0 = (t & 2047) * 4;
    int target = idx[n];
    float4 v = {0.f, 0.f, 0.f, 0.f};
    int r = target - k0;
    if (r >= 0 && r < 4) ((float*)&v)[r] = 1.0f;
    ((float4*)out1)[t] = v;
}

// ------------------------------------------------------------------ launch
extern "C" void kernel_launch(void* const* d_in, const int* in_sizes, int n_in,
                              void* d_out, int out_size, void* d_ws, size_t ws_size,
                              hipStream_t stream) {
    const float* x  = (const float*)d_in[0];   // [16][256][32][32]
    const float* cb = (const float*)d_in[1];   // [8192][256]
    float* out0 = (float*)d_out;                       // quantized
    float* out1 = (float*)d_out + 4194304;             // one_hot (537 MB)

    // small scratch in ws
    char* ws = (char*)d_ws;
    float* csq  = (float*)(ws + 0);            //  32 KB
    float* xsq  = (float*)(ws + 32768);        //  64 KB
    int*   idx  = (int*)  (ws + 98304);        //  64 KB

    // big scratch in the one_hot region (fully overwritten last by onehot)
    char* sc = (char*)out1;
    unsigned short* Xbf = (unsigned short*)sc;                   //  8 MB
    unsigned short* Cbf = (unsigned short*)(sc + 8388608);       //  4 MB
    float* xT  = (float*)(sc + 12582912);                        // 16 MB
    unsigned* sv0 = (unsigned*)(sc + 29360128);                  //  4 MB
    unsigned* sv1 = (unsigned*)(sc + 33554432);                  //  4 MB
    unsigned* sv2 = (unsigned*)(sc + 37748736);                  //  4 MB

    prep_x_kernel<<<4096, 256, 0, stream>>>(x, xT, Xbf);
    prep_c_kernel<<<2048, 256, 0, stream>>>(cb, Cbf);
    sumsq_kernel<<<K / 16, 256, 0, stream>>>(cb, csq, K);
    sumsq_kernel<<<NROWS / 16, 256, 0, stream>>>(xT, xsq, NROWS);

    dim3 sgrid(K / 128, NROWS / 64);   // (64 col-tiles fast, 256 row-tiles)
    screen_kernel<<<sgrid, 256, 0, stream>>>(Xbf, Cbf, csq, sv0, sv1, sv2);

    rescore_kernel<<<NROWS / 4, 256, 0, stream>>>(xT, cb, csq, xsq, sv0, sv1, sv2, idx);

    gather_quant_kernel<<<(4194304 / 4) / 256, 256, 0, stream>>>(cb, idx, out0);
    onehot_kernel<<<(134217728 / 4) / 256, 256, 0, stream>>>(idx, out1);
}

// Round 10
// 855.018 us; speedup vs baseline: 1.2525x; 1.2525x over previous
//
#include <hip/hip_runtime.h>
#include <float.h>
#include <stdint.h>

// Problem constants
constexpr int D      = 256;
constexpr int K      = 8192;
constexpr int NROWS  = 16384;   // 16 * 32 * 32
constexpr int BHW    = 1024;
constexpr float MARGIN = 8e-4f; // rigorous need: 5.8e-4 (2*bf16 err + 2 buckets) + pack slop

typedef __bf16 bf16x8 __attribute__((ext_vector_type(8)));
typedef float  f32x4  __attribute__((ext_vector_type(4)));
typedef unsigned short ushort4v __attribute__((ext_vector_type(4)));

// ---- contraction-proof f32 ops (round exactly like numpy's elementwise)
__device__ __forceinline__ float mul_rn(float a, float b) {
#pragma clang fp contract(off)
    return a * b;
}
__device__ __forceinline__ float add_rn(float a, float b) {
#pragma clang fp contract(off)
    return a + b;
}
__device__ __forceinline__ float sub_rn(float a, float b) {
#pragma clang fp contract(off)
    return a - b;
}

__device__ __forceinline__ unsigned short f32_bf16_rn(float f) {
    unsigned u = __float_as_uint(f);
    return (unsigned short)((u + 0x7FFFu + ((u >> 16) & 1u)) >> 16);
}

__device__ __forceinline__ unsigned umin_(unsigned a, unsigned b) { return a < b ? a : b; }
__device__ __forceinline__ unsigned umax_(unsigned a, unsigned b) { return a > b ? a : b; }

// monotone float->u32 key: order(key) == order(float)
__device__ __forceinline__ unsigned mono_key(float s) {
    unsigned b = __float_as_uint(s);
    return b ^ ((unsigned)((int)b >> 31) | 0x80000000u);
}
__device__ __forceinline__ float inv_mono(unsigned k) {
    unsigned m = (k & 0x80000000u) ? 0x80000000u : 0xFFFFFFFFu;
    return __uint_as_float(k ^ m);
}

__device__ __forceinline__ void async16(const void* g, void* l) {
    __builtin_amdgcn_global_load_lds(
        (const __attribute__((address_space(1))) unsigned int*)g,
        (__attribute__((address_space(3))) unsigned int*)l, 16, 0, 0);
}

// ---------------- K1: x (B,C,H,W) -> xT[n][256] f32 + Xbf[n][256] bf16
__global__ __launch_bounds__(256)
void prep_x_kernel(const float* __restrict__ x, float* __restrict__ xT,
                   unsigned short* __restrict__ Xbf) {
    __shared__ float t[32][33];
    const int tid = threadIdx.x;
    const int tx = tid & 31, ty = tid >> 5;
    const int ht = blockIdx.x & 31;
    const int dt = (blockIdx.x >> 5) & 7;
    const int b  = blockIdx.x >> 8;
    #pragma unroll
    for (int r = 0; r < 4; ++r) {
        int dl = ty + 8 * r;
        t[dl][tx] = x[(size_t)(b * 256 + dt * 32 + dl) * BHW + ht * 32 + tx];
    }
    __syncthreads();
    #pragma unroll
    for (int r = 0; r < 4; ++r) {
        int hwl = ty + 8 * r;
        int n = b * BHW + ht * 32 + hwl;
        float f = t[tx][hwl];
        xT[(size_t)n * 256 + dt * 32 + tx] = f;
        Xbf[(size_t)n * 256 + dt * 32 + tx] = f32_bf16_rn(f);
    }
}

// ---------------- K2: cb -> Cbf bf16
__global__ __launch_bounds__(256)
void prep_c_kernel(const float* __restrict__ cb, unsigned short* __restrict__ Cbf) {
    int t = blockIdx.x * 256 + threadIdx.x;   // one float4 (524288 total)
    float4 v = ((const float4*)cb)[t];
    ushort4v h;
    h.x = f32_bf16_rn(v.x); h.y = f32_bf16_rn(v.y);
    h.z = f32_bf16_rn(v.z); h.w = f32_bf16_rn(v.w);
    *(ushort4v*)(Cbf + (size_t)t * 4) = h;
}

// ---------------- K3: np-exact sum of squares, wave-parallel (bit-exact
// replica of numpy pairwise order for n=256: 2 halves x 8 chains x 16 adds)
__global__ __launch_bounds__(256)
void sumsq_kernel(const float* __restrict__ rows, float* __restrict__ out, int nrows) {
    const int tid  = threadIdx.x;
    const int ln   = tid & 63;
    const int sub  = ln & 15;
    const int h    = sub >> 3;
    const int j    = sub & 7;
    const int row  = blockIdx.x * 16 + (tid >> 4);
    if (row >= nrows) return;
    const float* p = rows + (size_t)row * 256 + h * 128 + j;
    float v = p[0];
    float r = mul_rn(v, v);
    #pragma unroll
    for (int i = 1; i < 16; ++i) {
        v = p[i * 8];
        r = add_rn(r, mul_rn(v, v));
    }
    float s = add_rn(r, __shfl_xor(r, 1, 64));
    s = add_rn(s, __shfl_xor(s, 2, 64));
    s = add_rn(s, __shfl_xor(s, 4, 64));
    float o = __shfl_xor(s, 8, 64);
    if (sub == 0) out[row] = add_rn(s, o);
}

// ---------------- K5: bf16 MFMA screen, packed-key top-3 per (row, 128-block)
// Coalesced global_load_lds staging (8 lanes = one row's 128 B k-chunk) with
// XOR swizzle baked into the SOURCE selection: LDS[r][s] = G[r][s ^ (r&7)]
// -> staging coalesced AND ds_read_b128 fragment reads are 2-way/free.
// Grid: (64 col-tiles fast, 128 row-tiles): XCD pins its 8 col-tiles of Cbf;
// consecutive blocks share one A-tile (L2-hot).
__global__ __launch_bounds__(256)
void screen_kernel(const unsigned short* __restrict__ Xbf,  // [16384][256]
                   const unsigned short* __restrict__ Cbf,  // [8192][256]
                   const float* __restrict__ csq,
                   unsigned* __restrict__ sv0, unsigned* __restrict__ sv1,
                   unsigned* __restrict__ sv2) {
    __shared__ __align__(16) unsigned short As[128 * 64];   // 16 KB  [row][64k swizzled]
    __shared__ __align__(16) unsigned short Bs[128 * 64];   // 16 KB

    const int tid = threadIdx.x;
    const int w   = tid >> 6;
    const int ln  = tid & 63;
    const int bx = blockIdx.x;      // col-tile (128 cols), 0..63  -- fast dim
    const int by = blockIdx.y;      // row-tile (128 rows), 0..127

    const int rh = (w & 1) * 64;    // wave's row half
    const int ch = (w >> 1) * 64;   // wave's col half

    // staging geometry: this wave covers rows [w*32, w*32+32) in 4 instrs of
    // 8 rows; lane ln: row = r0 + (ln>>3), slot = ln&7, fetches global chunk
    // (slot ^ (row&7)) of that row -> LDS[r][s] = G[r][s^(r&7)], coalesced.
    const int lrow_off = ln >> 3;          // 0..7
    const int slot     = ln & 7;           // 0..7

    f32x4 acc[4][4] = {};

    for (int kc = 0; kc < 4; ++kc) {               // K = 256 in chunks of 64
        const int kbase = kc * 64;
        #pragma unroll
        for (int t = 0; t < 4; ++t) {
            const int r0  = w * 32 + t * 8;        // wave-uniform
            const int row = r0 + lrow_off;
            const int ca  = slot ^ (row & 7);
            async16(Xbf + (size_t)(by * 128 + row) * 256 + kbase + ca * 8,
                    As + r0 * 64);
            async16(Cbf + (size_t)(bx * 128 + row) * 256 + kbase + ca * 8,
                    Bs + r0 * 64);
        }
        __syncthreads();   // stage visible (drains vmcnt)
        #pragma unroll
        for (int sub = 0; sub < 2; ++sub) {        // two 32-k MFMA steps
            bf16x8 af[4], bfr[4];
            #pragma unroll
            for (int t = 0; t < 4; ++t) {
                const int ra = rh + t * 16 + (ln & 15);
                const int sa = (sub * 4 + (ln >> 4)) ^ (ra & 7);
                af[t] = *(const bf16x8*)(As + ra * 64 + sa * 8);
                const int rb = ch + t * 16 + (ln & 15);
                const int sb = (sub * 4 + (ln >> 4)) ^ (rb & 7);
                bfr[t] = *(const bf16x8*)(Bs + rb * 64 + sb * 8);
            }
            #pragma unroll
            for (int i = 0; i < 4; ++i)
                #pragma unroll
                for (int j = 0; j < 4; ++j)
                    acc[i][j] = __builtin_amdgcn_mfma_f32_16x16x32_bf16(af[i], bfr[j], acc[i][j], 0, 0, 0);
        }
        __syncthreads();   // all reads done before restage
    }

    float cq[4];
    #pragma unroll
    for (int j = 0; j < 4; ++j)
        cq[j] = csq[bx * 128 + ch + j * 16 + (ln & 15)];

    // LDS overlay for cross-wave merge (tiles dead now)
    unsigned* lmk0 = (unsigned*)As;        // [128][2]
    unsigned* lmk1 = lmk0 + 256;
    unsigned* lmk2 = lmk1 + 256;

    #pragma unroll
    for (int i = 0; i < 4; ++i)
        #pragma unroll
        for (int r = 0; r < 4; ++r) {
            unsigned k[4];
            #pragma unroll
            for (int j = 0; j < 4; ++j) {
                float s = fmaf(-2.0f, acc[i][j][r], cq[j]);   // == rn(cq - 2*acc)
                k[j] = (mono_key(s) & 0xFFFFFF80u) | (unsigned)(ch + j * 16 + (ln & 15));
            }
            // sort4 -> smallest 3
            unsigned t0 = umin_(k[0], k[1]), t1 = umax_(k[0], k[1]);
            unsigned t2 = umin_(k[2], k[3]), t3 = umax_(k[2], k[3]);
            unsigned a0 = umin_(t0, t2);
            unsigned u  = umax_(t0, t2), v = umin_(t1, t3);
            unsigned a1 = umin_(u, v);
            unsigned a2 = umax_(u, v);
            // 16-lane butterfly merge of sorted triples
            #pragma unroll
            for (int m = 1; m < 16; m <<= 1) {
                unsigned b0 = __shfl_xor(a0, m, 64);
                unsigned b1 = __shfl_xor(a1, m, 64);
                unsigned b2 = __shfl_xor(a2, m, 64);
                unsigned uu = umax_(a0, b0), tt = umin_(a1, b1);
                unsigned n0 = umin_(a0, b0);
                unsigned n1 = umin_(uu, tt);
                unsigned n2 = umin_(umin_(a2, b2), umax_(uu, tt));
                a0 = n0; a1 = n1; a2 = n2;
            }
            if ((ln & 15) == 0) {
                int lrow = rh + i * 16 + (ln >> 4) * 4 + r;   // 0..127
                int half = w >> 1;
                lmk0[lrow * 2 + half] = a0;
                lmk1[lrow * 2 + half] = a1;
                lmk2[lrow * 2 + half] = a2;
            }
        }
    __syncthreads();
    if (tid < 128) {
        unsigned q0 = lmk0[tid * 2], q1 = lmk1[tid * 2], q2 = lmk2[tid * 2];
        unsigned p0 = lmk0[tid * 2 + 1], p1 = lmk1[tid * 2 + 1], p2 = lmk2[tid * 2 + 1];
        unsigned uu = umax_(q0, p0), tt = umin_(q1, p1);
        unsigned n0 = umin_(q0, p0);
        unsigned n1 = umin_(uu, tt);
        unsigned n2 = umin_(umin_(q2, p2), umax_(uu, tt));
        size_t o = (size_t)bx * NROWS + by * 128 + tid;
        sv0[o] = n0; sv1[o] = n1; sv2[o] = n2;
    }
}

// ---------------- K6: fused flag + exact rescore -> idx[n]  (1 wave / row)
__global__ __launch_bounds__(256)
void rescore_kernel(const float* __restrict__ xT, const float* __restrict__ cb,
                    const float* __restrict__ csq, const float* __restrict__ xsq,
                    const unsigned* __restrict__ sv0, const unsigned* __restrict__ sv1,
                    const unsigned* __restrict__ sv2,
                    int* __restrict__ idx) {
    const int tid = threadIdx.x;
    const int w = tid >> 6, ln = tid & 63;
    const int n = blockIdx.x * 4 + w;
    unsigned k0 = sv0[(size_t)ln * NROWS + n];
    unsigned k1 = sv1[(size_t)ln * NROWS + n];
    unsigned k2 = sv2[(size_t)ln * NROWS + n];
    // global min key over 64 blocks
    unsigned g = k0;
    #pragma unroll
    for (int m = 1; m < 64; m <<= 1) g = umin_(g, __shfl_xor(g, m, 64));
    float th = inv_mono(g & 0xFFFFFF80u) + MARGIN;
    unsigned th_key = mono_key(th) | 127u;
    unsigned long long m1 = __ballot(k0 <= th_key);   // block winner is candidate
    unsigned long long m2 = __ballot(k1 <= th_key);   // runner-up is candidate
    unsigned long long m3 = __ballot(k2 <= th_key);   // >=3 near-ties: full scan

    float4 xv = ((const float4*)xT)[(size_t)n * 64 + ln];
    const float xs = xsq[n];
    float bs = FLT_MAX;
    int   bk = 0x7fffffff;
    auto eval = [&](int k) {
        float4 cv = ((const float4*)cb)[(size_t)k * 64 + ln];
        double d = (double)cv.x * xv.x + (double)cv.y * xv.y
                 + (double)cv.z * xv.z + (double)cv.w * xv.w;
        #pragma unroll
        for (int m = 1; m < 64; m <<= 1) d += __shfl_xor(d, m, 64);
        float s = sub_rn(add_rn(xs, csq[k]), mul_rn(2.0f, (float)d));
        if (s < bs || (s == bs && k < bk)) { bs = s; bk = k; }
    };
    while (m1) {
        int b = (int)__builtin_ctzll(m1); m1 &= m1 - 1;
        unsigned kb = __shfl((int)k0, b, 64);
        eval(b * 128 + (int)(kb & 127u));
    }
    while (m2) {
        int b = (int)__builtin_ctzll(m2); m2 &= m2 - 1;
        unsigned kb = __shfl((int)k1, b, 64);
        eval(b * 128 + (int)(kb & 127u));
    }
    while (m3) {   // rare rigorous fallback
        int b = (int)__builtin_ctzll(m3); m3 &= m3 - 1;
        for (int kk = 0; kk < 128; ++kk) eval(b * 128 + kk);
    }
    if (ln == 0) idx[n] = bk;
}

// ---------------- K7: quantized gather back to (B,C,H,W)
__global__ __launch_bounds__(256)
void gather_quant_kernel(const float* __restrict__ cb, const int* __restrict__ idx,
                         float* __restrict__ out0) {
    int t = blockIdx.x * 256 + threadIdx.x;
    int hw4 = t & 255;
    int d   = (t >> 8) & 255;
    int b   = t >> 16;
    int n0  = b * BHW + hw4 * 4;
    float4 o;
    o.x = cb[(size_t)idx[n0 + 0] * D + d];
    o.y = cb[(size_t)idx[n0 + 1] * D + d];
    o.z = cb[(size_t)idx[n0 + 2] * D + d];
    o.w = cb[(size_t)idx[n0 + 3] * D + d];
    ((float4*)out0)[t] = o;
}

// ---------------- K8: one-hot fill
__global__ __launch_bounds__(256)
void onehot_kernel(const int* __restrict__ idx, float* __restrict__ out1) {
    int t = blockIdx.x * 256 + threadIdx.x;
    int n  = t >> 11;
    int k0 = (t & 2047) * 4;
    int target = idx[n];
    float4 v = {0.f, 0.f, 0.f, 0.f};
    int r = target - k0;
    if (r >= 0 && r < 4) ((float*)&v)[r] = 1.0f;
    ((float4*)out1)[t] = v;
}

// ------------------------------------------------------------------ launch
extern "C" void kernel_launch(void* const* d_in, const int* in_sizes, int n_in,
                              void* d_out, int out_size, void* d_ws, size_t ws_size,
                              hipStream_t stream) {
    const float* x  = (const float*)d_in[0];   // [16][256][32][32]
    const float* cb = (const float*)d_in[1];   // [8192][256]
    float* out0 = (float*)d_out;                       // quantized
    float* out1 = (float*)d_out + 4194304;             // one_hot (537 MB)

    // small scratch in ws
    char* ws = (char*)d_ws;
    float* csq  = (float*)(ws + 0);            //  32 KB
    float* xsq  = (float*)(ws + 32768);        //  64 KB
    int*   idx  = (int*)  (ws + 98304);        //  64 KB

    // big scratch in the one_hot region (fully overwritten last by onehot)
    char* sc = (char*)out1;
    unsigned short* Xbf = (unsigned short*)sc;                   //  8 MB
    unsigned short* Cbf = (unsigned short*)(sc + 8388608);       //  4 MB
    float* xT  = (float*)(sc + 12582912);                        // 16 MB
    unsigned* sv0 = (unsigned*)(sc + 29360128);                  //  4 MB
    unsigned* sv1 = (unsigned*)(sc + 33554432);                  //  4 MB
    unsigned* sv2 = (unsigned*)(sc + 37748736);                  //  4 MB

    prep_x_kernel<<<4096, 256, 0, stream>>>(x, xT, Xbf);
    prep_c_kernel<<<2048, 256, 0, stream>>>(cb, Cbf);
    sumsq_kernel<<<K / 16, 256, 0, stream>>>(cb, csq, K);
    sumsq_kernel<<<NROWS / 16, 256, 0, stream>>>(xT, xsq, NROWS);

    dim3 sgrid(K / 128, NROWS / 128);   // (64 col-tiles fast, 128 row-tiles)
    screen_kernel<<<sgrid, 256, 0, stream>>>(Xbf, Cbf, csq, sv0, sv1, sv2);

    rescore_kernel<<<NROWS / 4, 256, 0, stream>>>(xT, cb, csq, xsq, sv0, sv1, sv2, idx);

    gather_quant_kernel<<<(4194304 / 4) / 256, 256, 0, stream>>>(cb, idx, out0);
    onehot_kernel<<<(134217728 / 4) / 256, 256, 0, stream>>>(idx, out1);
}